// Round 6
// baseline (207.158 us; speedup 1.0000x reference)
//
#include <hip/hip_runtime.h>

#define NJ 24
#define ROWF 99            // 24*4 quats + 3 pos
#define TT 2048
#define NROWS (64 * 2048)  // 131072
#define TROWS 32           // rows per block
#define BLOCK 64           // one wave; 2 lanes per row: even=X, odd=Y
#define NBLOCKS (NROWS / TROWS)   // 4096

// async global->LDS, size=4: lane L writes lds_base + L*4; global addr = gp + OFF
// (OFF must be an integer constant expression -> template parameter)
template<int OFF>
__device__ __forceinline__ void glds4(const float* gp, float* lp) {
  __builtin_amdgcn_global_load_lds(
      (const __attribute__((address_space(1))) void*)gp,
      (__attribute__((address_space(3))) void*)lp, 4, OFF, 0);
}

// One issue pair (X and Y) for sub-index I of chunk C into buffer S.
// Transposed layout: unit u = f*32 + r (f = float-in-chunk, r = row).
// Issue I covers u = 64I..64I+63: lane L -> f = 2I + (L>>5), r = L&31;
// global float = (row0 + r)*99 + C*32 + f = [axg/ayg per-lane base] + C*128 + I*8 bytes.
#define GI(C, S, I)                                                  \
  glds4<(C)*128 + (I)*8>(axg, &buf[S][0][(I)*64]);                   \
  glds4<(C)*128 + (I)*8>(ayg, &buf[S][1][(I)*64]);

#define ISSUE_CHUNK(C, S) do {                                       \
  GI(C, S, 0)  GI(C, S, 1)  GI(C, S, 2)  GI(C, S, 3)                 \
  GI(C, S, 4)  GI(C, S, 5)  GI(C, S, 6)  GI(C, S, 7)                 \
  GI(C, S, 8)  GI(C, S, 9)  GI(C, S, 10) GI(C, S, 11)                \
  GI(C, S, 12) GI(C, S, 13) GI(C, S, 14) GI(C, S, 15)                \
} while (0)

__device__ __forceinline__ void quat2mat(float w, float x, float y, float z, float* R) {
  float s = 2.0f / (w*w + x*x + y*y + z*z);      // matches reference (unnormalized q)
  float xx = s*x*x, yy = s*y*y, zz = s*z*z;
  float xy = s*x*y, xz = s*x*z, yz = s*y*z;
  float xw = s*x*w, yw = s*y*w, zw = s*z*w;
  R[0] = 1.0f - (yy+zz); R[1] = xy - zw;        R[2] = xz + yw;
  R[3] = xy + zw;        R[4] = 1.0f - (xx+zz); R[5] = yz - xw;
  R[6] = xz - yw;        R[7] = yz + xw;        R[8] = 1.0f - (xx+yy);
}

__device__ __forceinline__ void mm3(const float* A, const float* B, float* C) {
#pragma unroll
  for (int r = 0; r < 3; ++r)
#pragma unroll
    for (int c = 0; c < 3; ++c)
      C[3*r+c] = fmaf(A[3*r], B[c], fmaf(A[3*r+1], B[3+c], A[3*r+2]*B[6+c]));
}

#define QMSE(q0, q1, q2, q3) ({ \
  float _n  = sqrtf((q0)*(q0) + (q1)*(q1) + (q2)*(q2) + (q3)*(q3)); \
  float _iv = 1.0f / fmaxf(_n, 1e-12f); \
  float _a0 = (q0)*_iv, _a1 = (q1)*_iv, _a2 = (q2)*_iv, _a3 = (q3)*_iv; \
  float _d0 = _a0 - __shfl_xor(_a0, 1, 64); \
  float _d1 = _a1 - __shfl_xor(_a1, 1, 64); \
  float _d2 = _a2 - __shfl_xor(_a2, 1, 64); \
  float _d3 = _a3 - __shfl_xor(_a3, 1, 64); \
  _d0*_d0 + _d1*_d1 + _d2*_d2 + _d3*_d3; })

#define TDIFF(t0, t1, t2) ({ \
  float _e0 = (t0) - __shfl_xor((t0), 1, 64); \
  float _e1 = (t1) - __shfl_xor((t1), 1, 64); \
  float _e2 = (t2) - __shfl_xor((t2), 1, 64); \
  _e0*_e0 + _e1*_e1 + _e2*_e2; })

// quat read from transposed chunk: float 4*cc+j of row rr at unit (4cc+j)*32+rr.
// Bank = rr for all components -> X/Y lane pair shares a bank = free 2-way.
#define STEP(qb, c, cc, GP, TP, GO, TO) do { \
  float q0 = (qb)[(((cc)*4+0)<<5) + rr], q1 = (qb)[(((cc)*4+1)<<5) + rr]; \
  float q2 = (qb)[(((cc)*4+2)<<5) + rr], q3 = (qb)[(((cc)*4+3)<<5) + rr]; \
  rot_acc += QMSE(q0, q1, q2, q3); \
  float R[9]; quat2mat(q0, q1, q2, q3, R); \
  mm3(GP, R, GO); \
  float v0 = tv[3*(c)], v1 = tv[3*(c)+1], v2 = tv[3*(c)+2]; \
  TO[0] = fmaf(GP[0], v0, fmaf(GP[1], v1, fmaf(GP[2], v2, TP[0]))); \
  TO[1] = fmaf(GP[3], v0, fmaf(GP[4], v1, fmaf(GP[5], v2, TP[1]))); \
  TO[2] = fmaf(GP[6], v0, fmaf(GP[7], v1, fmaf(GP[8], v2, TP[2]))); \
  gacc += TDIFF(TO[0], TO[1], TO[2]); \
} while (0)

#define LEAF(qb, c, cc, GP, TP) do { \
  float q0 = (qb)[(((cc)*4+0)<<5) + rr], q1 = (qb)[(((cc)*4+1)<<5) + rr]; \
  float q2 = (qb)[(((cc)*4+2)<<5) + rr], q3 = (qb)[(((cc)*4+3)<<5) + rr]; \
  rot_acc += QMSE(q0, q1, q2, q3); \
  float v0 = tv[3*(c)], v1 = tv[3*(c)+1], v2 = tv[3*(c)+2]; \
  float t0 = fmaf(GP[0], v0, fmaf(GP[1], v1, fmaf(GP[2], v2, TP[0]))); \
  float t1 = fmaf(GP[3], v0, fmaf(GP[4], v1, fmaf(GP[5], v2, TP[1]))); \
  float t2 = fmaf(GP[6], v0, fmaf(GP[7], v1, fmaf(GP[8], v2, TP[2]))); \
  gacc += TDIFF(t0, t1, t2); \
} while (0)

__global__ __launch_bounds__(BLOCK, 4) void motion_loss_kernel(
    const float* __restrict__ Ym, const float* __restrict__ Xm,
    const float* __restrict__ Yt, const float* __restrict__ Xt,
    float* __restrict__ out) {
  // [bufsel][X/Y][transposed 32 floats x 32 rows] = 16 KB + tv 576 B -> 9 blocks/CU
  __shared__ float buf[2][2][1024];
  __shared__ float tvX[72], tvY[72];

  const int lane = threadIdx.x;
  const size_t row0 = (size_t)blockIdx.x * TROWS;   // 32 | 2048 -> single batch
  const int b = (int)(row0 >> 11);

  // staging source: per-lane float offset Pf = r*99 + (L>>5), r = L&31
  const int Pf = (lane & 31) * ROWF + (lane >> 5);
  const float* axg = Xm + row0 * ROWF + Pf;
  const float* ayg = Ym + row0 * ROWF + Pf;

  const int par = lane & 1;                         // 0 = X chain, 1 = Y chain
  const int rr  = lane >> 1;                        // row 0..31

  // root position (floats 96..98) direct to registers, under the c0 shadow
  const float* posp = (par ? Ym : Xm) + (row0 + rr) * ROWF + 96;
  float p0 = posp[0], p1 = posp[1], p2 = posp[2];

  ISSUE_CHUNK(0, 0);                                // joints 0..7 -> buf0
#pragma unroll
  for (int k = 0; k < 3; ++k) {                     // 144 tv floats
    int id = k * BLOCK + lane;
    if (id < 72) tvX[id] = Xt[(size_t)b * 72 + id];
    else if (id < 144) tvY[id - 72] = Yt[(size_t)b * 72 + (id - 72)];
  }
  __syncthreads();                                  // c0 (+pos, tv) ready
  ISSUE_CHUNK(1, 1);                                // joints 8..15 -> buf1 (async)

  const float* tv  = par ? tvY : tvX;
  const float* qb0 = &buf[0][0][0] + par * 1024;
  const float* qb1 = &buf[1][0][0] + par * 1024;

  float rot_acc = 0.0f, gacc = 0.0f;
  float GA[9], GB[9], GC[9], GD[9];
  float TA[3], TB[3], TC[3], TD[3];

  // ---- chunk 0: root + joints 1..7 ----
  {
    float q0 = qb0[(0<<5)+rr], q1 = qb0[(1<<5)+rr];
    float q2 = qb0[(2<<5)+rr], q3 = qb0[(3<<5)+rr];
    rot_acc += QMSE(q0, q1, q2, q3);
    quat2mat(q0, q1, q2, q3, GA);
  }
  TA[0] = p0; TA[1] = p1; TA[2] = p2;
  float rootd2 = TDIFF(TA[0], TA[1], TA[2]);
  gacc += rootd2;

  // TOPOLOGY = [-1,0,0,0,1,2,3,4,5,6,7,8,9,9,9,12,13,14,16,17,18,19,20,21]
  STEP(qb0, 1, 1, GA, TA, GB, TB);
  STEP(qb0, 2, 2, GA, TA, GC, TC);
  STEP(qb0, 3, 3, GA, TA, GD, TD);
  STEP(qb0, 4, 4, GB, TB, GA, TA);
  STEP(qb0, 5, 5, GC, TC, GB, TB);
  STEP(qb0, 6, 6, GD, TD, GC, TC);
  STEP(qb0, 7, 7, GA, TA, GD, TD);
  __syncthreads();                                  // c1 ready; buf0 reads retired
  ISSUE_CHUNK(2, 0);                                // joints 16..23 -> buf0 (async)

  // ---- chunk 1: joints 8..15 ----
  STEP(qb1,  8, 0, GB, TB, GA, TA);
  STEP(qb1,  9, 1, GC, TC, GB, TB);
  LEAF(qb1, 10, 2, GD, TD);
  LEAF(qb1, 11, 3, GA, TA);
  STEP(qb1, 12, 4, GB, TB, GC, TC);
  STEP(qb1, 13, 5, GB, TB, GD, TD);
  STEP(qb1, 14, 6, GB, TB, GA, TA);
  LEAF(qb1, 15, 7, GC, TC);
  __syncthreads();                                  // c2 ready

  // ---- chunk 2: joints 16..23 ----
  STEP(qb0, 16, 0, GD, TD, GB, TB);
  STEP(qb0, 17, 1, GA, TA, GC, TC);
  STEP(qb0, 18, 2, GB, TB, GD, TD);
  STEP(qb0, 19, 3, GC, TC, GA, TA);
  STEP(qb0, 20, 4, GD, TD, GB, TB);
  STEP(qb0, 21, 5, GA, TA, GC, TC);
  LEAF(qb0, 22, 6, GB, TB);
  LEAF(qb0, 23, 7, GC, TC);

  const float c_rot = 1.0f / ((float)NROWS * NJ * 4);   // B1 * mean over (bs,T,24,4)
  const float c_gtr = 2.5f / ((float)NROWS * NJ * 3);   // B2*2.5 * mean over (bs,T,24,3)
  const float c_pos = 1.0f / ((float)NROWS * 3);        // B2 * mean over (bs,T,3)
  // 0.5: X/Y lane pairs accumulate identical squared diffs
  float contrib = 0.5f * (c_rot * rot_acc + c_gtr * gacc + c_pos * rootd2);
#pragma unroll
  for (int o = 32; o > 0; o >>= 1) contrib += __shfl_down(contrib, o, 64);
  if (lane == 0) atomicAdd(out, contrib);
}

extern "C" void kernel_launch(void* const* d_in, const int* in_sizes, int n_in,
                              void* d_out, int out_size, void* d_ws, size_t ws_size,
                              hipStream_t stream) {
  const float* Ym = (const float*)d_in[0];
  const float* Xm = (const float*)d_in[1];
  const float* Yt = (const float*)d_in[2];
  const float* Xt = (const float*)d_in[3];
  float* out = (float*)d_out;
  (void)hipMemsetAsync(out, 0, sizeof(float), stream);
  motion_loss_kernel<<<NBLOCKS, BLOCK, 0, stream>>>(Ym, Xm, Yt, Xt, out);
}